// Round 6
// baseline (867.751 us; speedup 1.0000x reference)
//
#include <hip/hip_runtime.h>

// SparseSpikingConv2D — Round 5: fp32 conv, 4-pixel x 16-cout register blocking.
// R3/R4 identical 415us exposed the real limiter: 4 fma per 16B weight fetch
// (DS/SMEM pipe + dependency serialization). Now each weight ds_read_b128
// feeds 16 fma (4 pixels x 4 co). x taps via 3 clamped global loads (VMEM pipe
// idle), no shuffles. fp32 + borderline flagging; exact fp64 fixup pass.
// fma issue floor: 123 us.

constexpr int CIc = 64, COc = 128, HHc = 64, WWc = 64, NBc = 32;
constexpr float EPSB = 2e-4f;        // borderline band on mthr
constexpr unsigned CAPc = 1u << 20;  // fixup list capacity

// workspace layout (bytes)
constexpr size_t O_CNT   = 0;                    // 1 uint (padded 16)
constexpr size_t O_NORMD = 16;                   // 128 double
constexpr size_t O_RNORM = O_NORMD + 1024;       // 128 float
constexpr size_t O_WDT   = O_RNORM + 512;        // [co][t][ci] double = 589824 B
constexpr size_t O_LIST  = O_WDT + 589824;       // CAPc uint
constexpr size_t WS_NEED = O_LIST + (size_t)CAPc * 4;

// Parallel: 128 blocks x 64 lanes; lane sums 9 strided elems, butterfly fp64.
__global__ void norm_prep(const float* __restrict__ w, double* __restrict__ normd,
                          float* __restrict__ rnormf, unsigned* __restrict__ counter) {
    const int co = blockIdx.x;       // 0..127
    const int lane = threadIdx.x;    // 0..63
    double s = 0.0;
    #pragma unroll
    for (int k = 0; k < 9; ++k) {
        const double v = (double)w[(k * 64 + lane) * COc + co];
        s = fma(v, v, s);
    }
    #pragma unroll
    for (int off = 32; off; off >>= 1) s += __shfl_xor(s, off);
    if (lane == 0) {
        s += 1e-8;
        normd[co]  = s;
        rnormf[co] = (float)(1.0 / s);
        if (co == 0) counter[0] = 0u;
    }
}

// wdT[co][t][ci] = (double)w[t][ci][co]  (lane=ci coalesced in pass B)
__global__ void wT_prep(const float* __restrict__ w, double* __restrict__ wdT) {
    const int i = blockIdx.x * 256 + threadIdx.x;  // over 73728
    if (i >= 9 * CIc * COc) return;
    const int ci = i & 63, t = (i >> 6) % 9, co = i / (9 * 64);
    wdT[i] = (double)w[(t * CIc + ci) * COc + co];
}

// ---- Pass A: fp32 conv + LIF + spike + borderline flagging ----
// block (64,4): thread = 4 y-rows x 16 Cout. grid (4, 8, 32) = 1024 blocks.
__global__ __launch_bounds__(256, 4) void convA(
    const float* __restrict__ x,       // [32,64,64,64]
    const float* __restrict__ mem,     // [32,128,64,64]
    const float* __restrict__ w,       // [9,64,128]
    const float* __restrict__ beta_p,
    const float* __restrict__ bias,
    const float* __restrict__ rnormf,
    float* __restrict__ out_spk, float* __restrict__ out_mem,
    unsigned* __restrict__ counter, unsigned* __restrict__ list)
{
    __shared__ float lds_w[9 * CIc * 16];          // 36 KB: [t*64+ci][16 co]

    const int ix  = threadIdx.x;                   // 0..63
    const int py  = threadIdx.y;                   // 0..3 (wave id)
    const int iy0 = (blockIdx.x * 4 + py) * 4;     // first of 4 output rows
    const int co0 = blockIdx.y * 16;
    const int n   = blockIdx.z;

    // Stage weight slice -> LDS (2304 float4 / 256 threads = 9 iters).
    {
        const int tid = py * 64 + ix;
        const float4* __restrict__ wg = (const float4*)w;  // [row][32 float4]
        float4* __restrict__ ws4 = (float4*)lds_w;         // [row][4 float4]
        #pragma unroll
        for (int q = tid; q < 9 * CIc * 4; q += 256)
            ws4[q] = wg[(q >> 2) * 32 + (co0 >> 2) + (q & 3)];
    }
    __syncthreads();

    // Per-lane clamped x offsets + edge masks (only taps that leave the row).
    const int offL = max(ix - 1, 0);
    const int offR = min(ix + 1, 63);
    const float mL = (ix > 0)  ? 1.0f : 0.0f;
    const float mR = (ix < 63) ? 1.0f : 0.0f;

    // Input rows iy0-1 .. iy0+4 (clamped offsets, wave-uniform).
    int rowo[6];
    #pragma unroll
    for (int r = 0; r < 6; ++r)
        rowo[r] = min(max(iy0 + r - 1, 0), HHc - 1) * WWc;
    const bool topBad = (iy0 == 0);          // row r=0 invalid (wave-uniform)
    const bool botBad = (iy0 + 4 == HHc);    // row r=5 invalid (wave-uniform)

    float acc[4][16];
    #pragma unroll
    for (int p = 0; p < 4; ++p)
        #pragma unroll
        for (int j = 0; j < 16; ++j) acc[p][j] = 0.0f;

    const float* xb = x + (size_t)n * CIc * HHc * WWc;
    const float4* __restrict__ lw4 = (const float4*)lds_w;

    for (int ci = 0; ci < CIc; ++ci) {
        const float* xc = xb + ci * (HHc * WWc);

        // 6 input rows x {left,center,right}; edge-masked.
        float xv[6][3];
        #pragma unroll
        for (int r = 0; r < 6; ++r) {
            const float* xr = xc + rowo[r];
            xv[r][0] = xr[offL] * mL;
            xv[r][1] = xr[ix];
            xv[r][2] = xr[offR] * mR;
        }
        if (topBad) { xv[0][0] = 0.f; xv[0][1] = 0.f; xv[0][2] = 0.f; }
        if (botBad) { xv[5][0] = 0.f; xv[5][1] = 0.f; xv[5][2] = 0.f; }

        #pragma unroll
        for (int dy = 0; dy < 3; ++dy) {
            #pragma unroll
            for (int g = 0; g < 4; ++g) {
                const float4 w0 = lw4[((dy * 3 + 0) * CIc + ci) * 4 + g];
                const float4 w1 = lw4[((dy * 3 + 1) * CIc + ci) * 4 + g];
                const float4 w2 = lw4[((dy * 3 + 2) * CIc + ci) * 4 + g];
                #pragma unroll
                for (int p = 0; p < 4; ++p) {
                    const float l = xv[p + dy][0];
                    const float c = xv[p + dy][1];
                    const float r = xv[p + dy][2];
                    float* a = &acc[p][g * 4];
                    a[0] = fmaf(l, w0.x, a[0]); a[1] = fmaf(l, w0.y, a[1]);
                    a[2] = fmaf(l, w0.z, a[2]); a[3] = fmaf(l, w0.w, a[3]);
                    a[0] = fmaf(c, w1.x, a[0]); a[1] = fmaf(c, w1.y, a[1]);
                    a[2] = fmaf(c, w1.z, a[2]); a[3] = fmaf(c, w1.w, a[3]);
                    a[0] = fmaf(r, w2.x, a[0]); a[1] = fmaf(r, w2.y, a[1]);
                    a[2] = fmaf(r, w2.z, a[2]); a[3] = fmaf(r, w2.w, a[3]);
                }
            }
        }
    }

    const float beta = beta_p[0];
    const float omb  = 1.0f - beta;

    #pragma unroll
    for (int p = 0; p < 4; ++p) {
        const size_t base = (((size_t)n * COc + co0) * HHc + (iy0 + p)) * WWc + ix;
        #pragma unroll
        for (int j = 0; j < 16; ++j) {
            const size_t idx = base + (size_t)j * (HHc * WWc);
            const float nm   = fmaf(mem[idx], beta, acc[p][j] * omb);
            const float mthr = fmaf(nm, rnormf[co0 + j], -bias[co0 + j]);
            const int s = (mthr > 0.f) + (mthr > 1.f) + (mthr > 2.f) + (mthr > 3.f);
            out_spk[idx] = (float)s;
            out_mem[idx] = (s > 0) ? 0.0f : nm;

            const bool fl = (fabsf(mthr) < EPSB) | (fabsf(mthr - 1.f) < EPSB) |
                            (fabsf(mthr - 2.f) < EPSB) | (fabsf(mthr - 3.f) < EPSB);
            const unsigned long long msk = __ballot(fl);
            if (msk) {
                unsigned wbase = 0;
                if (ix == 0) wbase = atomicAdd(counter, (unsigned)__popcll(msk));
                wbase = __shfl(wbase, 0);
                if (fl) {
                    const unsigned pos =
                        wbase + (unsigned)__popcll(msk & ((1ull << ix) - 1ull));
                    if (pos < CAPc) list[pos] = (unsigned)idx;
                }
            }
        }
    }
}

// ---- Pass B: exact fp64 recompute of flagged pixels (wave per pixel, lane=ci) ----
__global__ __launch_bounds__(256) void fixB(
    const float* __restrict__ x, const float* __restrict__ mem,
    const float* __restrict__ beta_p, const float* __restrict__ bias,
    const double* __restrict__ normd, const double* __restrict__ wdT,
    const unsigned* __restrict__ counter, const unsigned* __restrict__ list,
    float* __restrict__ out_spk, float* __restrict__ out_mem)
{
    const int lane  = threadIdx.x & 63;
    const int wave  = blockIdx.x * 4 + (threadIdx.x >> 6);
    const int nwave = gridDim.x * 4;
    const unsigned cnt = min(counter[0], CAPc);
    const double beta = (double)beta_p[0];
    const double omb  = 1.0 - beta;

    for (unsigned p = wave; p < cnt; p += nwave) {
        const unsigned idx = list[p];
        const int xp = idx & 63, yp = (idx >> 6) & 63;
        const int co = (idx >> 12) & 127, n = idx >> 19;

        const float*  xc = x + ((size_t)n * CIc + lane) * (HHc * WWc);
        const double* wt = wdT + (size_t)co * 9 * CIc + lane;

        double a = 0.0;
        #pragma unroll
        for (int t = 0; t < 9; ++t) {
            const int yy = yp + t / 3 - 1, xx = xp + t % 3 - 1;
            const bool v = ((unsigned)yy < 64u) && ((unsigned)xx < 64u);
            const int yyc = min(max(yy, 0), 63), xxc = min(max(xx, 0), 63);
            const double xv = v ? (double)xc[yyc * WWc + xxc] : 0.0;
            a = fma(xv, wt[t * CIc], a);
        }
        #pragma unroll
        for (int off = 32; off; off >>= 1) a += __shfl_xor(a, off);

        if (lane == 0) {
            const double nm   = (double)mem[idx] * beta + a * omb;
            const double mthr = nm / normd[co] - (double)bias[co];
            const int s = (mthr > 0.) + (mthr > 1.) + (mthr > 2.) + (mthr > 3.);
            out_spk[idx] = (float)s;
            out_mem[idx] = (s > 0) ? 0.0f : (float)nm;
        }
    }
}

// ---- Fallback (ws too small): all-fp64 direct conv ----
__global__ __launch_bounds__(256) void conv_fp64_fb(
    const float* __restrict__ x, const float* __restrict__ mem,
    const float* __restrict__ w, const float* __restrict__ beta_p,
    const float* __restrict__ bias, const double* __restrict__ normd,
    float* __restrict__ out_spk, float* __restrict__ out_mem)
{
    const int ix = threadIdx.x, iy = blockIdx.x * 4 + threadIdx.y;
    const int co0 = blockIdx.y * 8, n = blockIdx.z;
    bool valid[9]; int xoff[9];
    #pragma unroll
    for (int kh = 0; kh < 3; ++kh) {
        const int yy = iy + kh - 1;
        #pragma unroll
        for (int kw = 0; kw < 3; ++kw) {
            const int xx = ix + kw - 1, t = kh * 3 + kw;
            valid[t] = ((unsigned)yy < 64u) && ((unsigned)xx < 64u);
            xoff[t]  = yy * WWc + xx;
        }
    }
    double acc[8];
    #pragma unroll
    for (int j = 0; j < 8; ++j) acc[j] = 0.0;
    const float* xb = x + (size_t)n * CIc * HHc * WWc;
    for (int ci = 0; ci < CIc; ++ci) {
        const float* xc = xb + (size_t)ci * HHc * WWc;
        #pragma unroll
        for (int t = 0; t < 9; ++t) {
            const double xv = valid[t] ? (double)xc[xoff[t]] : 0.0;
            const float* wt = w + ((size_t)t * CIc + ci) * COc + co0;
            #pragma unroll
            for (int j = 0; j < 8; ++j) acc[j] = fma(xv, (double)wt[j], acc[j]);
        }
    }
    const double beta = (double)beta_p[0], omb = 1.0 - beta;
    const size_t base = (((size_t)n * COc + co0) * HHc + iy) * WWc + ix;
    #pragma unroll
    for (int j = 0; j < 8; ++j) {
        const size_t idx = base + (size_t)j * (HHc * WWc);
        const double nm   = (double)mem[idx] * beta + acc[j] * omb;
        const double mthr = nm / normd[co0 + j] - (double)bias[co0 + j];
        const int s = (mthr > 0.) + (mthr > 1.) + (mthr > 2.) + (mthr > 3.);
        out_spk[idx] = (float)s;
        out_mem[idx] = (s > 0) ? 0.0f : (float)nm;
    }
}

extern "C" void kernel_launch(void* const* d_in, const int* in_sizes, int n_in,
                              void* d_out, int out_size, void* d_ws, size_t ws_size,
                              hipStream_t stream) {
    const float* x      = (const float*)d_in[0];
    const float* mem    = (const float*)d_in[1];
    const float* w      = (const float*)d_in[2];
    const float* beta_p = (const float*)d_in[3];
    const float* bias   = (const float*)d_in[4];

    float* out_spk = (float*)d_out;
    float* out_mem = out_spk + (size_t)NBc * COc * HHc * WWc;

    char* ws = (char*)d_ws;
    unsigned* counter = (unsigned*)(ws + O_CNT);
    double*   normd   = (double*)(ws + O_NORMD);
    float*    rnormf  = (float*)(ws + O_RNORM);
    double*   wdT     = (double*)(ws + O_WDT);
    unsigned* list    = (unsigned*)(ws + O_LIST);

    if (ws_size >= WS_NEED) {
        norm_prep<<<COc, 64, 0, stream>>>(w, normd, rnormf, counter);
        wT_prep<<<(9 * CIc * COc + 255) / 256, 256, 0, stream>>>(w, wdT);

        dim3 blkA(64, 4, 1);               // 256 threads
        dim3 grdA(4, COc / 16, NBc);       // 4 x 8 x 32 = 1024 blocks (4/CU)
        convA<<<grdA, blkA, 0, stream>>>(x, mem, w, beta_p, bias, rnormf,
                                         out_spk, out_mem, counter, list);
        fixB<<<512, 256, 0, stream>>>(x, mem, beta_p, bias, normd, wdT,
                                      counter, list, out_spk, out_mem);
    } else {
        norm_prep<<<COc, 64, 0, stream>>>(w, normd, rnormf, counter);
        dim3 blk(WWc, 4, 1);
        dim3 grd(HHc / 4, COc / 8, NBc);
        conv_fp64_fb<<<grd, blk, 0, stream>>>(x, mem, w, beta_p, bias, normd,
                                              out_spk, out_mem);
    }
}

// Round 7
// 562.164 us; speedup vs baseline: 1.5436x; 1.5436x over previous
//
#include <hip/hip_runtime.h>

// SparseSpikingConv2D — Round 6: R5 structure (4 px x 16 cout per thread,
// LDS-staged weights) with the spill fixed.
// R5 post-mortem: __launch_bounds__(256,4) capped VGPR at 64 vs ~115 live
// -> acc spill/fill in the ci loop -> FETCH 855 MB / WRITE 437 MB of scratch
// traffic, memory-bound at 681 us. Fix: __launch_bounds__(256,2) (cap 256).
// Pipe model: VALU 123 us (floor), DS-issue 77 us, VMEM ~77 us -> VALU-bound.
// fp32 + borderline flagging (|mthr-d| < 2e-4); exact fp64 fixup pass B.

constexpr int CIc = 64, COc = 128, HHc = 64, WWc = 64, NBc = 32;
constexpr float EPSB = 2e-4f;        // borderline band on mthr
constexpr unsigned CAPc = 1u << 20;  // fixup list capacity

// workspace layout (bytes)
constexpr size_t O_CNT   = 0;                    // 1 uint (padded 16)
constexpr size_t O_NORMD = 16;                   // 128 double
constexpr size_t O_RNORM = O_NORMD + 1024;       // 128 float
constexpr size_t O_WDT   = O_RNORM + 512;        // [co][t][ci] double = 589824 B
constexpr size_t O_LIST  = O_WDT + 589824;       // CAPc uint
constexpr size_t WS_NEED = O_LIST + (size_t)CAPc * 4;

// Fused prep: blocks 0..127 -> norm (co=bx, 64-lane fp64 butterfly);
// blocks 128..415 -> wdT transpose chunks.
__global__ void prep_kernel(const float* __restrict__ w, double* __restrict__ normd,
                            float* __restrict__ rnormf, double* __restrict__ wdT,
                            unsigned* __restrict__ counter) {
    const int bx = blockIdx.x;
    if (bx < 128) {
        const int co = bx, lane = threadIdx.x & 63;
        if (threadIdx.x >= 64) return;
        double s = 0.0;
        #pragma unroll
        for (int k = 0; k < 9; ++k) {
            const double v = (double)w[(k * 64 + lane) * COc + co];
            s = fma(v, v, s);
        }
        #pragma unroll
        for (int off = 32; off; off >>= 1) s += __shfl_xor(s, off);
        if (lane == 0) {
            s += 1e-8;
            normd[co]  = s;
            rnormf[co] = (float)(1.0 / s);
            if (co == 0) counter[0] = 0u;
        }
    } else {
        const int i = (bx - 128) * 256 + threadIdx.x;  // over 73728
        if (i >= 9 * CIc * COc) return;
        const int ci = i & 63, t = (i >> 6) % 9, co = i / (9 * 64);
        wdT[i] = (double)w[(t * CIc + ci) * COc + co];  // wdT[co][t][ci]
    }
}

// ---- Pass A: fp32 conv + LIF + spike + borderline flagging ----
// block (64,4): thread = 4 y-rows x 16 Cout. grid (4, 8, 32) = 1024 blocks.
// launch_bounds(256,2): VGPR cap 256; ~115 live regs, must NOT spill (R5!).
__global__ __launch_bounds__(256, 2) void convA(
    const float* __restrict__ x,       // [32,64,64,64]
    const float* __restrict__ mem,     // [32,128,64,64]
    const float* __restrict__ w,       // [9,64,128]
    const float* __restrict__ beta_p,
    const float* __restrict__ bias,
    const float* __restrict__ rnormf,
    float* __restrict__ out_spk, float* __restrict__ out_mem,
    unsigned* __restrict__ counter, unsigned* __restrict__ list)
{
    __shared__ float lds_w[9 * CIc * 16];          // 36 KB: [t*64+ci][16 co]

    const int ix  = threadIdx.x;                   // 0..63
    const int py  = threadIdx.y;                   // 0..3 (wave id)
    const int iy0 = (blockIdx.x * 4 + py) * 4;     // first of 4 output rows
    const int co0 = blockIdx.y * 16;
    const int n   = blockIdx.z;

    // Stage weight slice -> LDS (2304 float4 / 256 threads = 9 iters).
    {
        const int tid = py * 64 + ix;
        const float4* __restrict__ wg = (const float4*)w;  // [row][32 float4]
        float4* __restrict__ ws4 = (float4*)lds_w;         // [row][4 float4]
        #pragma unroll
        for (int q = tid; q < 9 * CIc * 4; q += 256)
            ws4[q] = wg[(q >> 2) * 32 + (co0 >> 2) + (q & 3)];
    }
    __syncthreads();

    // Per-lane clamped x offsets + edge masks.
    const int offL = max(ix - 1, 0);
    const int offR = min(ix + 1, 63);
    const float mL = (ix > 0)  ? 1.0f : 0.0f;
    const float mR = (ix < 63) ? 1.0f : 0.0f;

    // Input rows iy0-1 .. iy0+4 (clamped, wave-uniform).
    int rowo[6];
    #pragma unroll
    for (int r = 0; r < 6; ++r)
        rowo[r] = min(max(iy0 + r - 1, 0), HHc - 1) * WWc;
    const bool topBad = (iy0 == 0);
    const bool botBad = (iy0 + 4 == HHc);

    float acc[4][16];
    #pragma unroll
    for (int p = 0; p < 4; ++p)
        #pragma unroll
        for (int j = 0; j < 16; ++j) acc[p][j] = 0.0f;

    const float* xb = x + (size_t)n * CIc * HHc * WWc;
    const float4* __restrict__ lw4 = (const float4*)lds_w;

    for (int ci = 0; ci < CIc; ++ci) {
        const float* xc = xb + ci * (HHc * WWc);

        // 6 input rows x {left,center,right}; edge-masked.
        float xv[6][3];
        #pragma unroll
        for (int r = 0; r < 6; ++r) {
            const float* xr = xc + rowo[r];
            xv[r][0] = xr[offL] * mL;
            xv[r][1] = xr[ix];
            xv[r][2] = xr[offR] * mR;
        }
        if (topBad) { xv[0][0] = 0.f; xv[0][1] = 0.f; xv[0][2] = 0.f; }
        if (botBad) { xv[5][0] = 0.f; xv[5][1] = 0.f; xv[5][2] = 0.f; }

        #pragma unroll
        for (int dy = 0; dy < 3; ++dy) {
            #pragma unroll
            for (int g = 0; g < 4; ++g) {
                const float4 w0 = lw4[((dy * 3 + 0) * CIc + ci) * 4 + g];
                const float4 w1 = lw4[((dy * 3 + 1) * CIc + ci) * 4 + g];
                const float4 w2 = lw4[((dy * 3 + 2) * CIc + ci) * 4 + g];
                #pragma unroll
                for (int p = 0; p < 4; ++p) {
                    const float l = xv[p + dy][0];
                    const float c = xv[p + dy][1];
                    const float r = xv[p + dy][2];
                    float* a = &acc[p][g * 4];
                    a[0] = fmaf(l, w0.x, a[0]); a[1] = fmaf(l, w0.y, a[1]);
                    a[2] = fmaf(l, w0.z, a[2]); a[3] = fmaf(l, w0.w, a[3]);
                    a[0] = fmaf(c, w1.x, a[0]); a[1] = fmaf(c, w1.y, a[1]);
                    a[2] = fmaf(c, w1.z, a[2]); a[3] = fmaf(c, w1.w, a[3]);
                    a[0] = fmaf(r, w2.x, a[0]); a[1] = fmaf(r, w2.y, a[1]);
                    a[2] = fmaf(r, w2.z, a[2]); a[3] = fmaf(r, w2.w, a[3]);
                }
            }
        }
    }

    const float beta = beta_p[0];
    const float omb  = 1.0f - beta;

    #pragma unroll
    for (int p = 0; p < 4; ++p) {
        const size_t base = (((size_t)n * COc + co0) * HHc + (iy0 + p)) * WWc + ix;
        #pragma unroll
        for (int j = 0; j < 16; ++j) {
            const size_t idx = base + (size_t)j * (HHc * WWc);
            const float nm   = fmaf(mem[idx], beta, acc[p][j] * omb);
            const float mthr = fmaf(nm, rnormf[co0 + j], -bias[co0 + j]);
            const int s = (mthr > 0.f) + (mthr > 1.f) + (mthr > 2.f) + (mthr > 3.f);
            out_spk[idx] = (float)s;
            out_mem[idx] = (s > 0) ? 0.0f : nm;

            const bool fl = (fabsf(mthr) < EPSB) | (fabsf(mthr - 1.f) < EPSB) |
                            (fabsf(mthr - 2.f) < EPSB) | (fabsf(mthr - 3.f) < EPSB);
            const unsigned long long msk = __ballot(fl);
            if (msk) {
                unsigned wbase = 0;
                if (ix == 0) wbase = atomicAdd(counter, (unsigned)__popcll(msk));
                wbase = __shfl(wbase, 0);
                if (fl) {
                    const unsigned pos =
                        wbase + (unsigned)__popcll(msk & ((1ull << ix) - 1ull));
                    if (pos < CAPc) list[pos] = (unsigned)idx;
                }
            }
        }
    }
}

// ---- Pass B: exact fp64 recompute of flagged pixels (wave per pixel, lane=ci) ----
__global__ __launch_bounds__(256) void fixB(
    const float* __restrict__ x, const float* __restrict__ mem,
    const float* __restrict__ beta_p, const float* __restrict__ bias,
    const double* __restrict__ normd, const double* __restrict__ wdT,
    const unsigned* __restrict__ counter, const unsigned* __restrict__ list,
    float* __restrict__ out_spk, float* __restrict__ out_mem)
{
    const int lane  = threadIdx.x & 63;
    const int wave  = blockIdx.x * 4 + (threadIdx.x >> 6);
    const int nwave = gridDim.x * 4;
    const unsigned cnt = min(counter[0], CAPc);
    const double beta = (double)beta_p[0];
    const double omb  = 1.0 - beta;

    for (unsigned p = wave; p < cnt; p += nwave) {
        const unsigned idx = list[p];
        const int xp = idx & 63, yp = (idx >> 6) & 63;
        const int co = (idx >> 12) & 127, n = idx >> 19;

        const float*  xc = x + ((size_t)n * CIc + lane) * (HHc * WWc);
        const double* wt = wdT + (size_t)co * 9 * CIc + lane;

        double a = 0.0;
        #pragma unroll
        for (int t = 0; t < 9; ++t) {
            const int yy = yp + t / 3 - 1, xx = xp + t % 3 - 1;
            const bool v = ((unsigned)yy < 64u) && ((unsigned)xx < 64u);
            const int yyc = min(max(yy, 0), 63), xxc = min(max(xx, 0), 63);
            const double xv = v ? (double)xc[yyc * WWc + xxc] : 0.0;
            a = fma(xv, wt[t * CIc], a);
        }
        #pragma unroll
        for (int off = 32; off; off >>= 1) a += __shfl_xor(a, off);

        if (lane == 0) {
            const double nm   = (double)mem[idx] * beta + a * omb;
            const double mthr = nm / normd[co] - (double)bias[co];
            const int s = (mthr > 0.) + (mthr > 1.) + (mthr > 2.) + (mthr > 3.);
            out_spk[idx] = (float)s;
            out_mem[idx] = (s > 0) ? 0.0f : (float)nm;
        }
    }
}

// ---- Fallback (ws too small): all-fp64 direct conv ----
__global__ __launch_bounds__(256) void conv_fp64_fb(
    const float* __restrict__ x, const float* __restrict__ mem,
    const float* __restrict__ w, const float* __restrict__ beta_p,
    const float* __restrict__ bias, const double* __restrict__ normd,
    float* __restrict__ out_spk, float* __restrict__ out_mem)
{
    const int ix = threadIdx.x, iy = blockIdx.x * 4 + threadIdx.y;
    const int co0 = blockIdx.y * 8, n = blockIdx.z;
    bool valid[9]; int xoff[9];
    #pragma unroll
    for (int kh = 0; kh < 3; ++kh) {
        const int yy = iy + kh - 1;
        #pragma unroll
        for (int kw = 0; kw < 3; ++kw) {
            const int xx = ix + kw - 1, t = kh * 3 + kw;
            valid[t] = ((unsigned)yy < 64u) && ((unsigned)xx < 64u);
            xoff[t]  = yy * WWc + xx;
        }
    }
    double acc[8];
    #pragma unroll
    for (int j = 0; j < 8; ++j) acc[j] = 0.0;
    const float* xb = x + (size_t)n * CIc * HHc * WWc;
    for (int ci = 0; ci < CIc; ++ci) {
        const float* xc = xb + (size_t)ci * HHc * WWc;
        #pragma unroll
        for (int t = 0; t < 9; ++t) {
            const double xv = valid[t] ? (double)xc[xoff[t]] : 0.0;
            const float* wt = w + ((size_t)t * CIc + ci) * COc + co0;
            #pragma unroll
            for (int j = 0; j < 8; ++j) acc[j] = fma(xv, (double)wt[j], acc[j]);
        }
    }
    const double beta = (double)beta_p[0], omb = 1.0 - beta;
    const size_t base = (((size_t)n * COc + co0) * HHc + iy) * WWc + ix;
    #pragma unroll
    for (int j = 0; j < 8; ++j) {
        const size_t idx = base + (size_t)j * (HHc * WWc);
        const double nm   = (double)mem[idx] * beta + acc[j] * omb;
        const double mthr = nm / normd[co0 + j] - (double)bias[co0 + j];
        const int s = (mthr > 0.) + (mthr > 1.) + (mthr > 2.) + (mthr > 3.);
        out_spk[idx] = (float)s;
        out_mem[idx] = (s > 0) ? 0.0f : (float)nm;
    }
}

extern "C" void kernel_launch(void* const* d_in, const int* in_sizes, int n_in,
                              void* d_out, int out_size, void* d_ws, size_t ws_size,
                              hipStream_t stream) {
    const float* x      = (const float*)d_in[0];
    const float* mem    = (const float*)d_in[1];
    const float* w      = (const float*)d_in[2];
    const float* beta_p = (const float*)d_in[3];
    const float* bias   = (const float*)d_in[4];

    float* out_spk = (float*)d_out;
    float* out_mem = out_spk + (size_t)NBc * COc * HHc * WWc;

    char* ws = (char*)d_ws;
    unsigned* counter = (unsigned*)(ws + O_CNT);
    double*   normd   = (double*)(ws + O_NORMD);
    float*    rnormf  = (float*)(ws + O_RNORM);
    double*   wdT     = (double*)(ws + O_WDT);
    unsigned* list    = (unsigned*)(ws + O_LIST);

    if (ws_size >= WS_NEED) {
        prep_kernel<<<128 + 288, 256, 0, stream>>>(w, normd, rnormf, wdT, counter);

        dim3 blkA(64, 4, 1);               // 256 threads
        dim3 grdA(4, COc / 16, NBc);       // 4 x 8 x 32 = 1024 blocks
        convA<<<grdA, blkA, 0, stream>>>(x, mem, w, beta_p, bias, rnormf,
                                         out_spk, out_mem, counter, list);
        fixB<<<512, 256, 0, stream>>>(x, mem, beta_p, bias, normd, wdT,
                                      counter, list, out_spk, out_mem);
    } else {
        prep_kernel<<<128, 256, 0, stream>>>(w, normd, rnormf, wdT, counter);
        dim3 blk(WWc, 4, 1);
        dim3 grd(HHc / 4, COc / 8, NBc);
        conv_fp64_fb<<<grd, blk, 0, stream>>>(x, mem, w, beta_p, bias, normd,
                                              out_spk, out_mem);
    }
}